// Round 5
// baseline (194.820 us; speedup 1.0000x reference)
//
#include <hip/hip_runtime.h>
#include <hip/hip_bf16.h>

// GATConv N=50000, C=64, H=12, E=400000 (+N self loops), x-space aggregation:
//   y[d] = concat_h[ (sum_e w_eh x[s_e]) / (den_h*H) ] @ Wstack,  h never built.
// R9 (176us, k_fused 83): readlane/FMA inner loop -> VALU-throughput-bound.
// R10 FAILED, R11/R12 NEUTRAL: micro-edits; 40-VGPR live set is genuine.
// R13 (188us, k_fused 91): MFMA aggregation via LDS staging. VALU 72->22%
//   PROVED R9 was VALU-bound; but serial latency windows per node (wgather
//   -> exp -> ds -> gather-loop -> ds -> MFMA) + 3 blk/CU occupancy + 5.2M
//   bank conflicts made it stall-bound. MFMA structure right, plumbing wrong.
// R14 (this round): delete the windows, keep the MFMA.
//   (a) 32x32x16 MFMA: M=32ch x2 chunks, N=32(12 heads), K=16 slots ~ deg.
//       2 MFMAs/node; den via 16-wide wl-row sum (no 3rd MFMA, -16 VGPR).
//   (b) A-frags DIRECT from global: 8 ds_bpermute (srow from resident adj
//       regs) + 16 masked ushort loads per node -> no xs LDS (-20KB ->
//       4 blk/CU), no staging round-trip, no bank conflicts; the node's
//       global traffic (wgather || A-loads) is ONE latency window.
//   (c) depth-2 pipeline: issue(j+1) loads before compute(j) -> window
//       j+1 hides under compute j. Ping-pong regs + wl buffers, static idx.
//   deg>16 (P~0.8%): rare extra K=16 passes accumulate into same accs.
// No segment_max: exp(s)/sum exp(s) is exact here (logits O(few), fp32 exp).

typedef __bf16 bf16x8 __attribute__((ext_vector_type(8)));
typedef __bf16 bf16x4v __attribute__((ext_vector_type(4)));
typedef float  f32x4  __attribute__((ext_vector_type(4)));
typedef float  f32x16 __attribute__((ext_vector_type(16)));
typedef unsigned u32x4 __attribute__((ext_vector_type(4)));

#define HEADS 12
#define CH 64
#define HC 768
#define CAP 64
#define ACOLS 24      // a_all[n][0..11]=src logits, [12..23]=dst logits
#define ZST 872       // zt row stride (bf16): 12 h-blocks of 72 + pad
#define HST 72        // zt per-head stride (64 data + 8 pad)
#define WLST 24       // wl row stride (16 slots + 8 pad)

__global__ __launch_bounds__(256) void k_pre(
    const float* __restrict__ W,
    const float* __restrict__ att_src, const float* __restrict__ att_dst,
    int* __restrict__ cnt, __bf16* __restrict__ Wt2, __bf16* __restrict__ Vt,
    int N) {
    const int nb_z = (N + 255) >> 8;
    const int nb_w = (CH * HC) >> 8;           // 192
    int b = blockIdx.x, tid = threadIdx.x;
    if (b < nb_z) {                            // ---- cnt = 0 ----
        int i = b * 256 + tid;
        if (i < N) cnt[i] = 0;
        return;
    }
    b -= nb_z;
    if (b < nb_w) {                            // ---- Wt2 transpose ----
        int t = b * 256 + tid;
        int c = t / HC, kk = t % HC;
        int k = kk & 63;
        Wt2[t] = (__bf16)W[(size_t)k * HC + (kk - k) + c];
        return;
    }
    b -= nb_w;                                 // ---- Vt col b (0..31) ----
    if (b >= 2 * HEADS) {
        if (tid < CH) Vt[b * CH + tid] = (__bf16)0.f;
        return;
    }
    const float* att = (b < HEADS) ? att_src + b * CH
                                   : att_dst + (b - HEADS) * CH;
    int k = tid >> 2, cq = tid & 3;            // 64 k-rows x 4 c-quarters
    const float* wr = W + (size_t)k * HC + (b % HEADS) * CH + cq * 16;
    float s = 0.f;
#pragma unroll
    for (int j = 0; j < 16; ++j) s += wr[j] * att[cq * 16 + j];
    s += __shfl_xor(s, 1, 64);
    s += __shfl_xor(s, 2, 64);
    if (cq == 0) Vt[b * CH + k] = (__bf16)s;
}

__global__ __launch_bounds__(256) void k_main(
    const float* __restrict__ x, const int* __restrict__ ei,
    const __bf16* __restrict__ Vt,
    int* __restrict__ cnt, int* __restrict__ adj,
    __bf16* __restrict__ xb, float* __restrict__ a_all, int N, int E) {
    const int EP = E + N;
    const int nb_build = (EP + 255) >> 8;
    int b = blockIdx.x, tid = threadIdx.x;

    if (b < nb_build) {                        // ---- adjacency: SOURCE ids ----
        int e = b * 256 + tid;
        if (e < EP) {
            int d, s;
            if (e < E) { d = ei[E + e]; s = ei[e]; }
            else       { d = e - E;     s = d; }
            int pos = atomicAdd(&cnt[d], 1);
            if (pos < CAP) adj[d * CAP + pos] = s;
        }
        return;
    }
    b -= nb_build;                             // ---- a_all = x@V + xb ----
    int wave = tid >> 6, lane = tid & 63;
    int m = lane & 15, quad = lane >> 4;
    int m0 = b * 64 + wave * 16;
    int row = m0 + m;
    int rc = row < N ? row : N - 1;
    const float* xa = x + (size_t)rc * CH + quad * 8;
    f32x4 v0 = *(const f32x4*)xa;
    f32x4 v1 = *(const f32x4*)(xa + 4);
    f32x4 v2 = *(const f32x4*)(xa + 32);
    f32x4 v3 = *(const f32x4*)(xa + 36);
    bf16x8 a0, a1;
#pragma unroll
    for (int j = 0; j < 4; ++j) {
        a0[j] = (__bf16)v0[j]; a0[4 + j] = (__bf16)v1[j];
        a1[j] = (__bf16)v2[j]; a1[4 + j] = (__bf16)v3[j];
    }
    if (row < N) {                             // fused xb = bf16(x)
        *(bf16x8*)(xb + (size_t)row * CH + quad * 8) = a0;
        *(bf16x8*)(xb + (size_t)row * CH + quad * 8 + 32) = a1;
    }
#pragma unroll
    for (int t = 0; t < 2; ++t) {              // two 16-col tiles -> 24 cols
        const __bf16* bp = Vt + (size_t)(t * 16 + m) * CH + quad * 8;
        bf16x8 b0 = *(const bf16x8*)bp;
        bf16x8 b1 = *(const bf16x8*)(bp + 32);
        f32x4 acc = {0.f, 0.f, 0.f, 0.f};
        acc = __builtin_amdgcn_mfma_f32_16x16x32_bf16(a0, b0, acc, 0, 0, 0);
        acc = __builtin_amdgcn_mfma_f32_16x16x32_bf16(a1, b1, acc, 0, 0, 0);
        int col = t * 16 + m;
        if (col < ACOLS) {
#pragma unroll
            for (int r = 0; r < 4; ++r) {
                int rr = m0 + quad * 4 + r;
                if (rr < N) a_all[(size_t)rr * ACOLS + col] = acc[r];
            }
        }
    }
}

__global__ __launch_bounds__(256) void k_fused(
    const int* __restrict__ cnt, const int* __restrict__ adj,
    const float* __restrict__ a_all,
    const __bf16* __restrict__ xb, const __bf16* __restrict__ Wt2,
    const float* __restrict__ x, const float* __restrict__ bias,
    float* __restrict__ out, int N) {
    __shared__ __bf16 zt[16 * ZST];            // 27904 B
    __shared__ __bf16 wl_all[4][2][32 * WLST]; // 12288 B -> total 40192 (4 blk/CU)
    int lane = threadIdx.x & 63;
    int wave = __builtin_amdgcn_readfirstlane(threadIdx.x >> 6);
    int base = blockIdx.x * 16;
    int g = lane >> 5, m = lane & 31;          // A row / B col identity
    int ib4 = g * 32;                          // bpermute byte base (slot g*8+j)

    // one-time zero of this wave's wl buffers (rows 12..31 stay 0 forever;
    // rows 0..11 k0..15 are fully rewritten per node). Wave-private: no bar.
    {
        unsigned* wz = (unsigned*)&wl_all[wave][0][0];
#pragma unroll
        for (int t = 0; t < 12; ++t) wz[t * 64 + lane] = 0u;
    }

    // ---- prologue: 4 nodes' cnt + adj[0..31] ----
    int degj[4], slj[4], dcj[4];
#pragma unroll
    for (int j = 0; j < 4; ++j) {
        int d = base + wave * 4 + j;
        int dg = __builtin_amdgcn_readfirstlane(cnt[d]);
        degj[j] = dg < CAP ? dg : CAP;
        int sraw = 0;
        if (lane < 32) sraw = adj[d * CAP + lane];
        slj[j] = sraw < 0 ? 0 : (sraw >= N ? N - 1 : sraw);
    }

    const unsigned short* xbu = (const unsigned short*)xb;

    // ---- depth-2 staging (all static-indexed under unroll) ----
    f32x4 sg0[2], sg1[2], sg2[2];              // masked a_all[src] gathers
    unsigned sa0[2][8], sa1[2][8];             // A u16 stage (chunk0 / chunk1)
    float adfs[2][HEADS];                      // uniform d-side logits (SGPR)

    auto issue = [&](int j, int buf) {
        int d = base + wave * 4 + j;
        int dc = degj[j] < 16 ? degj[j] : 16;
        dcj[j] = dc;
        const float* ap = a_all + (size_t)d * ACOLS + HEADS;   // uniform
#pragma unroll
        for (int hh = 0; hh < HEADS; ++hh) adfs[buf][hh] = ap[hh];
        f32x4 z4 = {0.f, 0.f, 0.f, 0.f};
        sg0[buf] = z4; sg1[buf] = z4; sg2[buf] = z4;
        if (lane < dc) {                       // lane = slot
            const f32x4* p = (const f32x4*)(a_all + (size_t)slj[j] * ACOLS);
            sg0[buf] = p[0]; sg1[buf] = p[1]; sg2[buf] = p[2];
        }
#pragma unroll
        for (int j8 = 0; j8 < 8; ++j8) {       // A-frag rows: slot g*8+j8
            int srow = __builtin_amdgcn_ds_bpermute(ib4 + j8 * 4, slj[j]);
            int slot = g * 8 + j8;
            unsigned v0 = 0, v1 = 0;
            if (slot < dc) {
                size_t o = (size_t)srow * CH + m;
                v0 = xbu[o];                   // chunk0: channel m
                v1 = xbu[o + 32];              // chunk1: channel m+32
            }
            sa0[buf][j8] = v0;
            sa1[buf][j8] = v1;
        }
    };

    auto compute = [&](int j, int buf) {
        int nodeRow = wave * 4 + j;
        int d = base + nodeRow;
        int dc = dcj[j];
        int deg = degj[j];
        __bf16* wl = &wl_all[wave][buf][0];

        // weights from staged gathers
        float wv[HEADS];
        {
            float asf[HEADS];
#pragma unroll
            for (int u = 0; u < 4; ++u) {
                asf[u] = sg0[buf][u]; asf[4 + u] = sg1[buf][u]; asf[8 + u] = sg2[buf][u];
            }
#pragma unroll
            for (int hh = 0; hh < HEADS; ++hh) {
                float sc = asf[hh] + adfs[buf][hh];
                sc = sc > 0.f ? sc : 0.2f * sc;
                wv[hh] = (lane < dc) ? __expf(sc) : 0.f;   // dead slots -> 0
            }
        }
        if (lane < 16) {
#pragma unroll
            for (int hh = 0; hh < HEADS; ++hh)
                wl[hh * WLST + lane] = (__bf16)wv[hh];
        }

        // B frag (row m = head col, k = g*8..g*8+7) + den from full row
        bf16x8 bfrag = *(const bf16x8*)(wl + m * WLST + g * 8);
        float den = 0.f;
        {
            bf16x8 d0 = *(const bf16x8*)(wl + m * WLST);
            bf16x8 d1 = *(const bf16x8*)(wl + m * WLST + 8);
#pragma unroll
            for (int t = 0; t < 8; ++t) den += (float)d0[t] + (float)d1[t];
        }

        // A frags from staged u16s
        u32x4 p0, p1;
#pragma unroll
        for (int t = 0; t < 4; ++t) {
            p0[t] = (sa0[buf][2 * t] & 0xffffu) | (sa0[buf][2 * t + 1] << 16);
            p1[t] = (sa1[buf][2 * t] & 0xffffu) | (sa1[buf][2 * t + 1] << 16);
        }
        bf16x8 a0f = __builtin_bit_cast(bf16x8, p0);
        bf16x8 a1f = __builtin_bit_cast(bf16x8, p1);

        f32x16 acc0, acc1;
#pragma unroll
        for (int t = 0; t < 16; ++t) { acc0[t] = 0.f; acc1[t] = 0.f; }
        acc0 = __builtin_amdgcn_mfma_f32_32x32x16_bf16(a0f, bfrag, acc0, 0, 0, 0);
        acc1 = __builtin_amdgcn_mfma_f32_32x32x16_bf16(a1f, bfrag, acc1, 0, 0, 0);

        if (deg > 16) {                        // rare (P~0.8%): extra K=16 passes
            int npass = (deg + 15) >> 4;
            for (int p = 1; p < npass; ++p) {
                int dcp = deg - 16 * p; if (dcp > 16) dcp = 16;
                int sid = 0;
                if (lane < 16) {
                    int sr = adj[d * CAP + 16 * p + lane];
                    sid = sr < 0 ? 0 : (sr >= N ? N - 1 : sr);
                }
                f32x4 q0 = {0.f,0.f,0.f,0.f}, q1 = q0, q2 = q0;
                if (lane < dcp) {
                    const f32x4* pp = (const f32x4*)(a_all + (size_t)sid * ACOLS);
                    q0 = pp[0]; q1 = pp[1]; q2 = pp[2];
                }
                float wp[HEADS];
#pragma unroll
                for (int u = 0; u < 4; ++u) {
                    wp[u]     = q0[u] + adfs[buf][u];
                    wp[4 + u] = q1[u] + adfs[buf][4 + u];
                    wp[8 + u] = q2[u] + adfs[buf][8 + u];
                }
#pragma unroll
                for (int hh = 0; hh < HEADS; ++hh) {
                    float sc = wp[hh];
                    sc = sc > 0.f ? sc : 0.2f * sc;
                    wp[hh] = (lane < dcp) ? __expf(sc) : 0.f;
                }
                if (lane < 16) {
#pragma unroll
                    for (int hh = 0; hh < HEADS; ++hh)
                        wl[hh * WLST + lane] = (__bf16)wp[hh];
                }
                u32x4 r0, r1;
#pragma unroll
                for (int j8 = 0; j8 < 8; ++j8) {
                    int srow = __builtin_amdgcn_ds_bpermute(ib4 + j8 * 4, sid);
                    int slot = g * 8 + j8;
                    unsigned v0 = 0, v1 = 0;
                    if (slot < dcp) {
                        size_t o = (size_t)srow * CH + m;
                        v0 = xbu[o]; v1 = xbu[o + 32];
                    }
                    if (j8 & 1) { r0[j8 >> 1] |= v0 << 16; r1[j8 >> 1] |= v1 << 16; }
                    else        { r0[j8 >> 1] = v0;        r1[j8 >> 1] = v1; }
                }
                bf16x8 bf2 = *(const bf16x8*)(wl + m * WLST + g * 8);
                bf16x8 e0 = *(const bf16x8*)(wl + m * WLST);
                bf16x8 e1 = *(const bf16x8*)(wl + m * WLST + 8);
#pragma unroll
                for (int t = 0; t < 8; ++t) den += (float)e0[t] + (float)e1[t];
                acc0 = __builtin_amdgcn_mfma_f32_32x32x16_bf16(
                    __builtin_bit_cast(bf16x8, r0), bf2, acc0, 0, 0, 0);
                acc1 = __builtin_amdgcn_mfma_f32_32x32x16_bf16(
                    __builtin_bit_cast(bf16x8, r1), bf2, acc1, 0, 0, 0);
            }
        }

        // epilogue: C/D row = (r&3) + 8*(r>>2) + 4g (+32*chunk), col = m
        float rinv = 1.0f / ((den + 1e-16f) * (float)HEADS);
        if (m < HEADS) {
            __bf16* zr = zt + nodeRow * ZST + m * HST;
#pragma unroll
            for (int ch = 0; ch < 2; ++ch) {
#pragma unroll
                for (int rr = 0; rr < 4; ++rr) {
                    int c0 = 8 * rr + 4 * g + 32 * ch;
                    bf16x4v pk;
#pragma unroll
                    for (int i = 0; i < 4; ++i) {
                        float v = ch ? acc1[4 * rr + i] : acc0[4 * rr + i];
                        pk[i] = (__bf16)(v * rinv);
                    }
                    *(bf16x4v*)(zr + c0) = pk;
                }
            }
        }
    };

    // ---- pipelined node loop ----
    issue(0, 0);
#pragma unroll
    for (int j = 0; j < 4; ++j) {
        if (j < 3) issue(j + 1, (j + 1) & 1);
        compute(j, j & 1);
    }

    __syncthreads();

    // ---- phase 3: 16x64x768 GEMM; wave = one 16-col tile (unchanged) ----
    {
        int mm = lane & 15, quad = lane >> 4;
        int n0 = wave * 16;
        const __bf16* za = zt + mm * ZST + quad * 8;
        const __bf16* wb = Wt2 + (size_t)(n0 + mm) * HC + quad * 8;
        f32x4 acc = {0.f, 0.f, 0.f, 0.f};
#pragma unroll
        for (int kc = 0; kc < HC; kc += 32) {
            int koff = ((kc >> 6) * HST) + (kc & 63);   // h-padded zt offset
            bf16x8 a  = *(const bf16x8*)(za + koff);
            bf16x8 bf = *(const bf16x8*)(wb + kc);
            acc = __builtin_amdgcn_mfma_f32_16x16x32_bf16(a, bf, acc, 0, 0, 0);
        }
        int col = n0 + mm;
        float bv = bias[col];
#pragma unroll
        for (int r = 0; r < 4; ++r) {
            int dd = base + quad * 4 + r;
            if (dd < N) {
                float o = x[(size_t)dd * CH + col] + acc[r] + bv;
                out[(size_t)dd * CH + col] = fmaxf(o, 0.f);
            }
        }
    }
}

extern "C" void kernel_launch(void* const* d_in, const int* in_sizes, int n_in,
                              void* d_out, int out_size, void* d_ws, size_t ws_size,
                              hipStream_t stream) {
    const float* x       = (const float*)d_in[0];
    const int*   ei      = (const int*)d_in[1];
    const float* W       = (const float*)d_in[2];
    const float* att_src = (const float*)d_in[3];
    const float* att_dst = (const float*)d_in[4];
    const float* bias    = (const float*)d_in[5];
    float* out = (float*)d_out;

    int N = in_sizes[0] / CH;   // 50000
    int E = in_sizes[1] / 2;    // 400000
    int EP = E + N;

    char* ws = (char*)d_ws;
    size_t off = 0;
    auto take = [&](size_t bytes) -> void* {
        void* p = ws + off;
        off = (off + bytes + 255) & ~(size_t)255;
        return p;
    };
    __bf16* xb    = (__bf16*)take((size_t)N * CH * sizeof(__bf16));
    __bf16* Wt2   = (__bf16*)take((size_t)CH * HC * sizeof(__bf16));
    __bf16* Vt    = (__bf16*)take((size_t)32 * CH * sizeof(__bf16));
    float*  a_all = (float*)take((size_t)N * ACOLS * sizeof(float));
    int*    adj   = (int*)take((size_t)N * CAP * sizeof(int));
    int*    cnt   = (int*)take((size_t)N * sizeof(int));

    const int nb_z     = (N + 255) / 256;
    const int nb_w     = (CH * HC) / 256;
    const int nb_build = (EP + 255) / 256;
    const int nb_ax    = (N + 63) / 64;

    k_pre<<<nb_z + nb_w + 32, 256, 0, stream>>>(W, att_src, att_dst, cnt, Wt2, Vt, N);
    k_main<<<nb_build + nb_ax, 256, 0, stream>>>(x, ei, Vt, cnt, adj, xb, a_all, N, E);
    k_fused<<<(N + 15) / 16, 256, 0, stream>>>(cnt, adj, a_all, xb, Wt2, x, bias, out, N);
}

// Round 6
// 176.766 us; speedup vs baseline: 1.1021x; 1.1021x over previous
//
#include <hip/hip_runtime.h>
#include <hip/hip_bf16.h>

// GATConv N=50000, C=64, H=12, E=400000 (+N self loops), x-space aggregation:
//   y[d] = concat_h[ (sum_e w_eh x[s_e]) / (den_h*H) ] @ Wstack,  h never built.
// R9 (176us, k_fused 83.5): readlane/FMA inner loop; VALU-throughput-bound.
// R10 FAILED, R11/R12 NEUTRAL (R12 k_fused 81.3 = best measured).
// R13 (91us) / R14 (98us): MFMA-aggregation restructures both stall-bound
//   (VALU 22-31%, MFMA 3%, occ 28%) -- too little work per latency window.
//   CONCLUSION: R9/R12 shape is the best known k_fused; restored exactly.
// R15 (this round): attack the NEVER-PROFILED half. In every round
//   total - k_fused ~= 90us = k_pre + k_main, invisible in top-5. Split
//   k_main into k_build (atomic adjacency) + k_ax (x@V MFMA + xb) so each
//   gets its own counters; accept losing their block-range overlap
//   (bounded ~10us) for attribution. k_build also gets 4-deep ILP:
//   grid-stride x4, all (d,s) loads issued before atomic+store chains.
// No segment_max: exp(s)/sum exp(s) is exact here (logits O(few), fp32 exp).

typedef __bf16 bf16x8 __attribute__((ext_vector_type(8)));
typedef float  f32x4  __attribute__((ext_vector_type(4)));
typedef float  f32x2  __attribute__((ext_vector_type(2)));

#define HEADS 12
#define CH 64
#define HC 768
#define CAP 64
#define ACOLS 24      // a_all[n][0..11]=src logits, [12..23]=dst logits
#define ZSTRIDE 776   // zt row stride (bf16)
#define EPT 4         // edges per thread in k_build

__device__ inline float readlane_f(float v, int lane) {
    return __builtin_bit_cast(float,
        __builtin_amdgcn_readlane(__builtin_bit_cast(int, v), lane));
}

__global__ __launch_bounds__(256) void k_pre(
    const float* __restrict__ W,
    const float* __restrict__ att_src, const float* __restrict__ att_dst,
    int* __restrict__ cnt, __bf16* __restrict__ Wt2, __bf16* __restrict__ Vt,
    int N) {
    const int nb_z = (N + 255) >> 8;
    const int nb_w = (CH * HC) >> 8;           // 192
    int b = blockIdx.x, tid = threadIdx.x;
    if (b < nb_z) {                            // ---- cnt = 0 ----
        int i = b * 256 + tid;
        if (i < N) cnt[i] = 0;
        return;
    }
    b -= nb_z;
    if (b < nb_w) {                            // ---- Wt2 transpose ----
        int t = b * 256 + tid;
        int c = t / HC, kk = t % HC;
        int k = kk & 63;
        Wt2[t] = (__bf16)W[(size_t)k * HC + (kk - k) + c];
        return;
    }
    b -= nb_w;                                 // ---- Vt col b (0..31) ----
    if (b >= 2 * HEADS) {
        if (tid < CH) Vt[b * CH + tid] = (__bf16)0.f;
        return;
    }
    const float* att = (b < HEADS) ? att_src + b * CH
                                   : att_dst + (b - HEADS) * CH;
    int k = tid >> 2, cq = tid & 3;            // 64 k-rows x 4 c-quarters
    const float* wr = W + (size_t)k * HC + (b % HEADS) * CH + cq * 16;
    float s = 0.f;
#pragma unroll
    for (int j = 0; j < 16; ++j) s += wr[j] * att[cq * 16 + j];
    s += __shfl_xor(s, 1, 64);
    s += __shfl_xor(s, 2, 64);
    if (cq == 0) Vt[b * CH + k] = (__bf16)s;
}

// ---- adjacency build, isolated for profiling; 4-deep ILP ----
__global__ __launch_bounds__(256) void k_build(
    const int* __restrict__ ei,
    int* __restrict__ cnt, int* __restrict__ adj, int N, int E) {
    const int EP = E + N;
    int tid0 = blockIdx.x * 256 + threadIdx.x;
    int T = gridDim.x * 256;                   // coalesced grid-stride
    int dv[EPT], sv[EPT];
#pragma unroll
    for (int k = 0; k < EPT; ++k) {            // phase A: all loads in flight
        int e = tid0 + k * T;
        dv[k] = -1; sv[k] = 0;
        if (e < EP) {
            if (e < E) { dv[k] = ei[E + e]; sv[k] = ei[e]; }
            else       { dv[k] = e - E;     sv[k] = dv[k]; }
        }
    }
#pragma unroll
    for (int k = 0; k < EPT; ++k) {            // phase B: atomic+store chains
        if (dv[k] >= 0) {
            int pos = atomicAdd(&cnt[dv[k]], 1);
            if (pos < CAP) adj[dv[k] * CAP + pos] = sv[k];
        }
    }
}

// ---- a_all = x@V + xb, isolated for profiling ----
__global__ __launch_bounds__(256) void k_ax(
    const float* __restrict__ x, const __bf16* __restrict__ Vt,
    __bf16* __restrict__ xb, float* __restrict__ a_all, int N) {
    int tid = threadIdx.x, b = blockIdx.x;
    int wave = tid >> 6, lane = tid & 63;
    int m = lane & 15, quad = lane >> 4;
    int m0 = b * 64 + wave * 16;
    int row = m0 + m;
    int rc = row < N ? row : N - 1;
    const float* xa = x + (size_t)rc * CH + quad * 8;
    f32x4 v0 = *(const f32x4*)xa;
    f32x4 v1 = *(const f32x4*)(xa + 4);
    f32x4 v2 = *(const f32x4*)(xa + 32);
    f32x4 v3 = *(const f32x4*)(xa + 36);
    bf16x8 a0, a1;
#pragma unroll
    for (int j = 0; j < 4; ++j) {
        a0[j] = (__bf16)v0[j]; a0[4 + j] = (__bf16)v1[j];
        a1[j] = (__bf16)v2[j]; a1[4 + j] = (__bf16)v3[j];
    }
    if (row < N) {                             // fused xb = bf16(x)
        *(bf16x8*)(xb + (size_t)row * CH + quad * 8) = a0;
        *(bf16x8*)(xb + (size_t)row * CH + quad * 8 + 32) = a1;
    }
#pragma unroll
    for (int t = 0; t < 2; ++t) {              // two 16-col tiles -> 24 cols
        const __bf16* bp = Vt + (size_t)(t * 16 + m) * CH + quad * 8;
        bf16x8 b0 = *(const bf16x8*)bp;
        bf16x8 b1 = *(const bf16x8*)(bp + 32);
        f32x4 acc = {0.f, 0.f, 0.f, 0.f};
        acc = __builtin_amdgcn_mfma_f32_16x16x32_bf16(a0, b0, acc, 0, 0, 0);
        acc = __builtin_amdgcn_mfma_f32_16x16x32_bf16(a1, b1, acc, 0, 0, 0);
        int col = t * 16 + m;
        if (col < ACOLS) {
#pragma unroll
            for (int r = 0; r < 4; ++r) {
                int rr = m0 + quad * 4 + r;
                if (rr < N) a_all[(size_t)rr * ACOLS + col] = acc[r];
            }
        }
    }
}

__global__ __launch_bounds__(256) void k_fused(
    const int* __restrict__ cnt, const int* __restrict__ adj,
    const float* __restrict__ a_all,
    const __bf16* __restrict__ xb, const __bf16* __restrict__ Wt2,
    const float* __restrict__ x, const float* __restrict__ bias,
    float* __restrict__ out, int N) {
    __shared__ __bf16 zt[16 * ZSTRIDE];
    int lane = threadIdx.x & 63;
    int wave = __builtin_amdgcn_readfirstlane(threadIdx.x >> 6);
    int base = blockIdx.x * 16;

    // ---- prologue: 4 nodes' cnt + adj[0..31] in parallel ----
    int degj[4], slj[4];
#pragma unroll
    for (int j = 0; j < 4; ++j) {
        int d = base + wave * 4 + j;
        int dg = __builtin_amdgcn_readfirstlane(cnt[d]);
        degj[j] = dg < CAP ? dg : CAP;
        int sraw = 0;
        if (lane < 32) sraw = adj[d * CAP + lane];   // half row; poison past deg
        slj[j] = sraw;
    }

#pragma unroll
    for (int j = 0; j < 4; ++j) {
        int row = wave * 4 + j;
        int d = base + row;
        int deg = degj[j];
        int s_l = slj[j];
        if (deg > 32 && lane >= 32)              // ~never (Poisson(9))
            s_l = adj[d * CAP + lane];
        s_l = s_l < 0 ? 0 : (s_l >= N ? N - 1 : s_l);  // clamp poison

        // ---- phase 1: lane = edge slot; 12 weights in VGPRs ----
        float adf[HEADS];
        {
            const f32x4* p = (const f32x4*)(a_all + (size_t)d * ACOLS + HEADS);
            f32x4 t0 = p[0], t1 = p[1], t2 = p[2];
#pragma unroll
            for (int u = 0; u < 4; ++u) { adf[u] = t0[u]; adf[4 + u] = t1[u]; adf[8 + u] = t2[u]; }
        }
        float w[HEADS];
        {
            const f32x4* p = (const f32x4*)(a_all + (size_t)s_l * ACOLS);
            f32x4 t0 = p[0], t1 = p[1], t2 = p[2];
            float asf[HEADS];
#pragma unroll
            for (int u = 0; u < 4; ++u) { asf[u] = t0[u]; asf[4 + u] = t1[u]; asf[8 + u] = t2[u]; }
#pragma unroll
            for (int hh = 0; hh < HEADS; ++hh) {
                float sc = asf[hh] + adf[hh];
                sc = sc > 0.f ? sc : 0.2f * sc;
                w[hh] = __expf(sc);              // lanes >= deg never read
            }
        }

        // ---- phase 2: readlane broadcast, {acc,den} f32x2 packed ----
        f32x2 acc2[HEADS];
#pragma unroll
        for (int hh = 0; hh < HEADS; ++hh) acc2[hh] = (f32x2){0.f, 0.f};
        int i = 0;
        for (; i + 3 < deg; i += 4) {
            int s0 = __builtin_amdgcn_readlane(s_l, i);
            int s1 = __builtin_amdgcn_readlane(s_l, i + 1);
            int s2 = __builtin_amdgcn_readlane(s_l, i + 2);
            int s3 = __builtin_amdgcn_readlane(s_l, i + 3);
            f32x2 xv0 = {(float)xb[(size_t)s0 * CH + lane], 1.f};
            f32x2 xv1 = {(float)xb[(size_t)s1 * CH + lane], 1.f};
            f32x2 xv2 = {(float)xb[(size_t)s2 * CH + lane], 1.f};
            f32x2 xv3 = {(float)xb[(size_t)s3 * CH + lane], 1.f};
#pragma unroll
            for (int hh = 0; hh < HEADS; ++hh) {
                float w0 = readlane_f(w[hh], i);
                float w1 = readlane_f(w[hh], i + 1);
                float w2 = readlane_f(w[hh], i + 2);
                float w3 = readlane_f(w[hh], i + 3);
                acc2[hh] += (f32x2){w0, w0} * xv0;
                acc2[hh] += (f32x2){w1, w1} * xv1;
                acc2[hh] += (f32x2){w2, w2} * xv2;
                acc2[hh] += (f32x2){w3, w3} * xv3;
            }
        }
        for (; i < deg; ++i) {
            int s = __builtin_amdgcn_readlane(s_l, i);
            f32x2 xv = {(float)xb[(size_t)s * CH + lane], 1.f};
#pragma unroll
            for (int hh = 0; hh < HEADS; ++hh) {
                float wv = readlane_f(w[hh], i);
                acc2[hh] += (f32x2){wv, wv} * xv;
            }
        }
        __bf16* zr = zt + row * ZSTRIDE + lane;
#pragma unroll
        for (int hh = 0; hh < HEADS; ++hh)
            zr[hh * CH] = (__bf16)(acc2[hh].x * (1.0f / ((acc2[hh].y + 1e-16f) * HEADS)));
    }

    __syncthreads();

    // ---- phase 3: 16x64x768 GEMM; wave = one 16-col tile ----
    {
        int m = lane & 15, quad = lane >> 4;
        int n0 = wave * 16;
        const __bf16* za = zt + m * ZSTRIDE + quad * 8;
        const __bf16* wb = Wt2 + (size_t)(n0 + m) * HC + quad * 8;
        f32x4 acc = {0.f, 0.f, 0.f, 0.f};
#pragma unroll
        for (int kc = 0; kc < HC; kc += 32) {
            bf16x8 a  = *(const bf16x8*)(za + kc);
            bf16x8 bf = *(const bf16x8*)(wb + kc);
            acc = __builtin_amdgcn_mfma_f32_16x16x32_bf16(a, bf, acc, 0, 0, 0);
        }
        int col = n0 + m;
        float bv = bias[col];
#pragma unroll
        for (int r = 0; r < 4; ++r) {
            int dd = base + quad * 4 + r;
            if (dd < N) {
                float o = x[(size_t)dd * CH + col] + acc[r] + bv;
                out[(size_t)dd * CH + col] = fmaxf(o, 0.f);
            }
        }
    }
}

extern "C" void kernel_launch(void* const* d_in, const int* in_sizes, int n_in,
                              void* d_out, int out_size, void* d_ws, size_t ws_size,
                              hipStream_t stream) {
    const float* x       = (const float*)d_in[0];
    const int*   ei      = (const int*)d_in[1];
    const float* W       = (const float*)d_in[2];
    const float* att_src = (const float*)d_in[3];
    const float* att_dst = (const float*)d_in[4];
    const float* bias    = (const float*)d_in[5];
    float* out = (float*)d_out;

    int N = in_sizes[0] / CH;   // 50000
    int E = in_sizes[1] / 2;    // 400000
    int EP = E + N;

    char* ws = (char*)d_ws;
    size_t off = 0;
    auto take = [&](size_t bytes) -> void* {
        void* p = ws + off;
        off = (off + bytes + 255) & ~(size_t)255;
        return p;
    };
    __bf16* xb    = (__bf16*)take((size_t)N * CH * sizeof(__bf16));
    __bf16* Wt2   = (__bf16*)take((size_t)CH * HC * sizeof(__bf16));
    __bf16* Vt    = (__bf16*)take((size_t)32 * CH * sizeof(__bf16));
    float*  a_all = (float*)take((size_t)N * ACOLS * sizeof(float));
    int*    adj   = (int*)take((size_t)N * CAP * sizeof(int));
    int*    cnt   = (int*)take((size_t)N * sizeof(int));

    const int nb_z     = (N + 255) / 256;
    const int nb_w     = (CH * HC) / 256;
    const int nb_build = (EP + EPT * 256 - 1) / (EPT * 256);   // 440
    const int nb_ax    = (N + 63) / 64;

    k_pre<<<nb_z + nb_w + 32, 256, 0, stream>>>(W, att_src, att_dst, cnt, Wt2, Vt, N);
    k_build<<<nb_build, 256, 0, stream>>>(ei, cnt, adj, N, E);
    k_ax<<<nb_ax, 256, 0, stream>>>(x, Vt, xb, a_all, N);
    k_fused<<<(N + 15) / 16, 256, 0, stream>>>(cnt, adj, a_all, xb, Wt2, x, bias, out, N);
}